// Round 2
// baseline (750.229 us; speedup 1.0000x reference)
//
#include <hip/hip_runtime.h>
#include <math.h>

// Problem dims (fixed by setup_inputs)
constexpr int B  = 128;
constexpr int DZ = 1024;
constexpr int L  = 4096;
constexpr int D  = 256;
constexpr int S  = 7;          // n_shifts_total
constexpr float EPS = 1e-8f;

static __device__ __forceinline__ float softplusf(float x) {
    // stable: max(x,0) + log1p(exp(-|x|))
    return fmaxf(x, 0.0f) + log1pf(expf(-fabsf(x)));
}

// ---------------------------------------------------------------------------
// Kernel A: per-batch dense heads.
// grid = B, block = 256 (== D)
// Computes k[b,:], knorm[b], shift[b,0:7] (softmax'd), beta[b], gate[b], gamma[b]
// ---------------------------------------------------------------------------
__global__ __launch_bounds__(256) void heads_kernel(
    const float* __restrict__ Z,
    const float* __restrict__ key_W, const float* __restrict__ key_b,
    const float* __restrict__ shift_W, const float* __restrict__ shift_b,
    const float* __restrict__ beta_W, const float* __restrict__ beta_b,
    const float* __restrict__ gate_W, const float* __restrict__ gate_b,
    const float* __restrict__ gamma_W, const float* __restrict__ gamma_b,
    float* __restrict__ k_out, float* __restrict__ knorm_out,
    float* __restrict__ shift_out, float* __restrict__ beta_out,
    float* __restrict__ gate_out, float* __restrict__ gamma_out)
{
    const int b = blockIdx.x;
    const int t = threadIdx.x;           // 0..255, one output channel of k each

    __shared__ float zrow[DZ];           // 4 KiB
    __shared__ float red[256];

    for (int i = t; i < DZ; i += 256) zrow[i] = Z[b * DZ + i];
    __syncthreads();

    // ---- k = tanh(Z @ key_W + key_b), one column per thread (coalesced key_W reads)
    float a0 = 0.f, a1 = 0.f, a2 = 0.f, a3 = 0.f;
    for (int z = 0; z < DZ; z += 4) {
        a0 = fmaf(zrow[z + 0], key_W[(z + 0) * D + t], a0);
        a1 = fmaf(zrow[z + 1], key_W[(z + 1) * D + t], a1);
        a2 = fmaf(zrow[z + 2], key_W[(z + 2) * D + t], a2);
        a3 = fmaf(zrow[z + 3], key_W[(z + 3) * D + t], a3);
    }
    float kv = tanhf((a0 + a1) + (a2 + a3) + key_b[t]);
    k_out[b * D + t] = kv;

    // ---- knorm = ||k||_2
    red[t] = kv * kv;
    __syncthreads();
    for (int st = 128; st > 0; st >>= 1) {
        if (t < st) red[t] += red[t + st];
        __syncthreads();
    }
    if (t == 0) knorm_out[b] = sqrtf(red[0]);

    // ---- 10 small dots: shift logits (7), beta, gate, gamma
    float part[10];
#pragma unroll
    for (int j = 0; j < 10; ++j) part[j] = 0.f;
    for (int z = t; z < DZ; z += 256) {
        const float zv = zrow[z];
#pragma unroll
        for (int j = 0; j < S; ++j) part[j] = fmaf(zv, shift_W[z * S + j], part[j]);
        part[7] = fmaf(zv, beta_W[z],  part[7]);
        part[8] = fmaf(zv, gate_W[z],  part[8]);
        part[9] = fmaf(zv, gamma_W[z], part[9]);
    }
#pragma unroll
    for (int j = 0; j < 10; ++j) {
        __syncthreads();
        red[t] = part[j];
        __syncthreads();
        for (int st = 128; st > 0; st >>= 1) {
            if (t < st) red[t] += red[t + st];
            __syncthreads();
        }
        if (t == 0) part[j] = red[0];
    }

    if (t == 0) {
        // shift softmax over 7
        float logits[S];
        float mx = -1e30f;
#pragma unroll
        for (int j = 0; j < S; ++j) {
            logits[j] = part[j] + shift_b[j];
            mx = fmaxf(mx, logits[j]);
        }
        float sum = 0.f;
#pragma unroll
        for (int j = 0; j < S; ++j) {
            logits[j] = expf(logits[j] - mx);
            sum += logits[j];
        }
        const float inv = 1.f / sum;
#pragma unroll
        for (int j = 0; j < S; ++j) shift_out[b * S + j] = logits[j] * inv;

        beta_out[b]  = softplusf(part[7] + beta_b[0]);
        gate_out[b]  = 1.f / (1.f + expf(-(part[8] + gate_b[0])));
        gamma_out[b] = softplusf(part[9] + gamma_b[0]) + 1.0f;
    }
}

// ---------------------------------------------------------------------------
// Kernel B: the 512 MiB streamer.
// s[b,l] = beta[b] * dot(M[b,l,:], k[b,:]) / (knorm[b]*||M[b,l,:]|| + EPS)
// One wave (64 lanes) per row l: lane loads float4 (16 B), fused dot + sumsq,
// 6-step shfl_xor reduce. Block = 4 waves, each wave does 4 rows -> 16 rows/blk.
// grid = B * L / 16 = 32768 blocks.
// ---------------------------------------------------------------------------
constexpr int ROWS_PER_BLOCK = 16;

__global__ __launch_bounds__(256) void sim_kernel(
    const float* __restrict__ M,
    const float* __restrict__ k,
    const float* __restrict__ knorm,
    const float* __restrict__ beta,
    float* __restrict__ s_out)
{
    const int blk   = blockIdx.x;
    const int b     = blk / (L / ROWS_PER_BLOCK);
    const int chunk = blk % (L / ROWS_PER_BLOCK);
    const int wave  = threadIdx.x >> 6;   // 0..3
    const int lane  = threadIdx.x & 63;

    __shared__ float4 k_lds[64];
    if (threadIdx.x < 64) k_lds[threadIdx.x] = ((const float4*)(k + b * D))[threadIdx.x];
    __syncthreads();

    const float4 kv = k_lds[lane];
    const float  kn = knorm[b];
    const float  bt = beta[b];

    const int l0 = chunk * ROWS_PER_BLOCK + wave * 4;
    const float4* Mrow0 = (const float4*)(M + ((size_t)b * L + l0) * D);

    // issue all 4 row loads up front (independent), then reduce each
    float4 mv[4];
#pragma unroll
    for (int r = 0; r < 4; ++r) mv[r] = Mrow0[(size_t)r * (D / 4) + lane];

#pragma unroll
    for (int r = 0; r < 4; ++r) {
        float dot = mv[r].x * kv.x + mv[r].y * kv.y + mv[r].z * kv.z + mv[r].w * kv.w;
        float msq = mv[r].x * mv[r].x + mv[r].y * mv[r].y + mv[r].z * mv[r].z + mv[r].w * mv[r].w;
#pragma unroll
        for (int off = 32; off > 0; off >>= 1) {
            dot += __shfl_xor(dot, off);
            msq += __shfl_xor(msq, off);
        }
        if (lane == 0) {
            const float sim = dot / (kn * sqrtf(msq) + EPS);
            s_out[(size_t)b * L + l0 + r] = bt * sim;
        }
    }
}

// ---------------------------------------------------------------------------
// Kernel C: per-row finish. grid = B, block = 256, 16 elements per thread.
// softmax(s) over L -> gate-interpolate with W_old -> circular 7-tap conv
// (row staged in LDS) -> pow(gamma) -> normalize -> out.
// ---------------------------------------------------------------------------
__global__ __launch_bounds__(256) void finish_kernel(
    const float* __restrict__ s,
    const float* __restrict__ W_old,
    const float* __restrict__ shiftv,
    const float* __restrict__ gate,
    const float* __restrict__ gamma,
    float* __restrict__ out)
{
    const int b = blockIdx.x;
    const int t = threadIdx.x;

    __shared__ float w[L];       // 16 KiB
    __shared__ float red[256];
    __shared__ float sh[S];

    // load s row; track max
    float vals[16];
    float mx = -1e30f;
#pragma unroll
    for (int i = 0; i < 16; ++i) {
        vals[i] = s[(size_t)b * L + t + i * 256];
        mx = fmaxf(mx, vals[i]);
    }
    red[t] = mx;
    __syncthreads();
    for (int st = 128; st > 0; st >>= 1) {
        if (t < st) red[t] = fmaxf(red[t], red[t + st]);
        __syncthreads();
    }
    mx = red[0];
    __syncthreads();

    float sum = 0.f;
#pragma unroll
    for (int i = 0; i < 16; ++i) {
        vals[i] = expf(vals[i] - mx);
        sum += vals[i];
    }
    red[t] = sum;
    __syncthreads();
    for (int st = 128; st > 0; st >>= 1) {
        if (t < st) red[t] += red[t + st];
        __syncthreads();
    }
    const float invsum = 1.f / red[0];
    __syncthreads();

    const float g = gate[b];
#pragma unroll
    for (int i = 0; i < 16; ++i) {
        const int l = t + i * 256;
        w[l] = fmaf(g, W_old[(size_t)b * L + l], (1.f - g) * (vals[i] * invsum));
    }
    if (t < S) sh[t] = shiftv[b * S + t];
    __syncthreads();

    // circular conv: W'[l] = sum_n sh[n] * w[(l - n + 3) mod L], then pow(gamma)
    const float gm = gamma[b];
    float pv[16];
    float psum = 0.f;
#pragma unroll
    for (int i = 0; i < 16; ++i) {
        const int l = t + i * 256;
        float acc = 0.f;
#pragma unroll
        for (int n = 0; n < S; ++n)
            acc = fmaf(sh[n], w[(l - n + 3 + L) & (L - 1)], acc);
        const float p = powf(acc, gm);
        pv[i] = p;
        psum += p;
    }
    red[t] = psum;
    __syncthreads();
    for (int st = 128; st > 0; st >>= 1) {
        if (t < st) red[t] += red[t + st];
        __syncthreads();
    }
    const float invp = 1.f / red[0];
#pragma unroll
    for (int i = 0; i < 16; ++i)
        out[(size_t)b * L + t + i * 256] = pv[i] * invp;
}

// ---------------------------------------------------------------------------
extern "C" void kernel_launch(void* const* d_in, const int* in_sizes, int n_in,
                              void* d_out, int out_size, void* d_ws, size_t ws_size,
                              hipStream_t stream)
{
    const float* Z       = (const float*)d_in[0];
    const float* W_old   = (const float*)d_in[1];
    const float* M       = (const float*)d_in[2];
    const float* key_W   = (const float*)d_in[3];
    const float* key_b   = (const float*)d_in[4];
    const float* shift_W = (const float*)d_in[5];
    const float* shift_b = (const float*)d_in[6];
    const float* beta_W  = (const float*)d_in[7];
    const float* beta_b  = (const float*)d_in[8];
    const float* gate_W  = (const float*)d_in[9];
    const float* gate_b  = (const float*)d_in[10];
    const float* gamma_W = (const float*)d_in[11];
    const float* gamma_b = (const float*)d_in[12];
    float* out = (float*)d_out;

    // workspace layout (floats)
    float* ws     = (float*)d_ws;
    float* k      = ws;                  // B*D    = 32768
    float* knorm  = k + B * D;           // 128
    float* shiftv = knorm + B;           // B*S    = 896
    float* betav  = shiftv + B * S;      // 128
    float* gatev  = betav + B;           // 128
    float* gammav = gatev + B;           // 128
    float* s      = gammav + B;          // B*L    = 524288
    // total ~2.23 MB of ws

    heads_kernel<<<B, 256, 0, stream>>>(Z, key_W, key_b, shift_W, shift_b,
                                        beta_W, beta_b, gate_W, gate_b,
                                        gamma_W, gamma_b,
                                        k, knorm, shiftv, betav, gatev, gammav);

    sim_kernel<<<B * (L / ROWS_PER_BLOCK), 256, 0, stream>>>(M, k, knorm, betav, s);

    finish_kernel<<<B, 256, 0, stream>>>(s, W_old, shiftv, gatev, gammav, out);
}

// Round 3
// 738.624 us; speedup vs baseline: 1.0157x; 1.0157x over previous
//
#include <hip/hip_runtime.h>
#include <math.h>

// Problem dims (fixed by setup_inputs)
constexpr int B  = 128;
constexpr int DZ = 1024;
constexpr int L  = 4096;
constexpr int D  = 256;
constexpr int S  = 7;          // n_shifts_total
constexpr float EPS = 1e-8f;

static __device__ __forceinline__ float softplusf(float x) {
    return fmaxf(x, 0.0f) + log1pf(expf(-fabsf(x)));
}

// ---------------------------------------------------------------------------
// Kernel A: per-batch dense heads. grid = B, block = 256 (== D)
// k[b,:] (tanh GEMV, unroll-16 for 16 loads in flight), plus ONE batched
// 11-row LDS tree reduction for {7 shift logits, beta, gate, gamma, ||k||^2}.
// ---------------------------------------------------------------------------
__global__ __launch_bounds__(256) void heads_kernel(
    const float* __restrict__ Z,
    const float* __restrict__ key_W, const float* __restrict__ key_b,
    const float* __restrict__ shift_W, const float* __restrict__ shift_b,
    const float* __restrict__ beta_W, const float* __restrict__ beta_b,
    const float* __restrict__ gate_W, const float* __restrict__ gate_b,
    const float* __restrict__ gamma_W, const float* __restrict__ gamma_b,
    float* __restrict__ k_out, float* __restrict__ knorm_out,
    float* __restrict__ shift_out, float* __restrict__ beta_out,
    float* __restrict__ gate_out, float* __restrict__ gamma_out)
{
    const int b = blockIdx.x;
    const int t = threadIdx.x;           // one k-column per thread

    constexpr int RSTRIDE = 257;         // pad to break bank aliasing
    __shared__ float zrow[DZ];           // 4 KiB
    __shared__ float red[11 * RSTRIDE];  // ~11.3 KiB

    for (int i = t; i < DZ; i += 256) zrow[i] = Z[b * DZ + i];
    __syncthreads();

    // ---- k = tanh(Z @ key_W + key_b): 16 independent loads in flight
    float acc = 0.f;
    for (int zb = 0; zb < DZ; zb += 16) {
        float p = 0.f;
#pragma unroll
        for (int u = 0; u < 16; ++u)
            p = fmaf(zrow[zb + u], key_W[(zb + u) * D + t], p);
        acc += p;
    }
    const float kv = tanhf(acc + key_b[t]);
    k_out[b * D + t] = kv;

    // ---- 10 small dots + kv^2, all reduced in one batched tree
    float part[11];
#pragma unroll
    for (int j = 0; j < 11; ++j) part[j] = 0.f;
    for (int z = t; z < DZ; z += 256) {
        const float zv = zrow[z];
#pragma unroll
        for (int j = 0; j < S; ++j) part[j] = fmaf(zv, shift_W[z * S + j], part[j]);
        part[7] = fmaf(zv, beta_W[z],  part[7]);
        part[8] = fmaf(zv, gate_W[z],  part[8]);
        part[9] = fmaf(zv, gamma_W[z], part[9]);
    }
    part[10] = kv * kv;

#pragma unroll
    for (int j = 0; j < 11; ++j) red[j * RSTRIDE + t] = part[j];
    __syncthreads();
    for (int st = 128; st > 0; st >>= 1) {
        if (t < st) {
#pragma unroll
            for (int j = 0; j < 11; ++j)
                red[j * RSTRIDE + t] += red[j * RSTRIDE + t + st];
        }
        __syncthreads();
    }

    if (t == 0) {
        float logits[S];
        float mx = -1e30f;
#pragma unroll
        for (int j = 0; j < S; ++j) {
            logits[j] = red[j * RSTRIDE] + shift_b[j];
            mx = fmaxf(mx, logits[j]);
        }
        float sum = 0.f;
#pragma unroll
        for (int j = 0; j < S; ++j) {
            logits[j] = expf(logits[j] - mx);
            sum += logits[j];
        }
        const float inv = 1.f / sum;
#pragma unroll
        for (int j = 0; j < S; ++j) shift_out[b * S + j] = logits[j] * inv;

        beta_out[b]  = softplusf(red[7 * RSTRIDE] + beta_b[0]);
        gate_out[b]  = 1.f / (1.f + expf(-(red[8 * RSTRIDE] + gate_b[0])));
        gamma_out[b] = softplusf(red[9 * RSTRIDE] + gamma_b[0]) + 1.0f;
        knorm_out[b] = sqrtf(red[10 * RSTRIDE]);
    }
}

// ---------------------------------------------------------------------------
// Kernel B: the 512 MiB streamer.
// 16 lanes per row (lane loads 4x float4 = 64 B of the 1 KB row), so the
// cross-lane reduce is 4 shfl_xor steps x 2 values = 2 DS ops/row (was 12).
// Each wave: 4 rows per pass x 4 passes = 16 rows, double-buffered prefetch.
// Block = 4 waves -> 64 rows; grid = B * L/64 = 8192.
// ---------------------------------------------------------------------------
__global__ __launch_bounds__(256) void sim_kernel(
    const float* __restrict__ M,
    const float* __restrict__ k,
    const float* __restrict__ knorm,
    const float* __restrict__ beta,
    float* __restrict__ s_out)
{
    const int blk   = blockIdx.x;
    const int b     = blk >> 6;          // 64 chunks per batch
    const int chunk = blk & 63;
    const int wave  = threadIdx.x >> 6;
    const int lane  = threadIdx.x & 63;
    const int sub   = lane >> 4;         // row within pass group (0..3)
    const int l16   = lane & 15;         // lane within row

    // k fragment for this lane's 64-B segment pattern (L2-resident, tiny)
    const float4* kp = (const float4*)(k + b * D);
    float4 kv[4];
#pragma unroll
    for (int j = 0; j < 4; ++j) kv[j] = kp[l16 + 16 * j];

    const float kn = knorm[b];
    const float bt = beta[b];

    const int l0 = chunk * 64 + wave * 16;            // wave covers rows l0..l0+15
    const float4* Mp = (const float4*)(M + ((size_t)b * L + l0) * D);  // row = 64 float4

    float4 mv[2][4];
#pragma unroll
    for (int j = 0; j < 4; ++j)
        mv[0][j] = Mp[(size_t)sub * 64 + l16 + 16 * j];

#pragma unroll
    for (int p = 0; p < 4; ++p) {
        if (p < 3) {
#pragma unroll
            for (int j = 0; j < 4; ++j)
                mv[(p + 1) & 1][j] = Mp[(size_t)((p + 1) * 4 + sub) * 64 + l16 + 16 * j];
        }
        const float4* m = mv[p & 1];
        float dot = 0.f, msq = 0.f;
#pragma unroll
        for (int j = 0; j < 4; ++j) {
            dot = fmaf(m[j].x, kv[j].x, dot); msq = fmaf(m[j].x, m[j].x, msq);
            dot = fmaf(m[j].y, kv[j].y, dot); msq = fmaf(m[j].y, m[j].y, msq);
            dot = fmaf(m[j].z, kv[j].z, dot); msq = fmaf(m[j].z, m[j].z, msq);
            dot = fmaf(m[j].w, kv[j].w, dot); msq = fmaf(m[j].w, m[j].w, msq);
        }
#pragma unroll
        for (int off = 8; off > 0; off >>= 1) {
            dot += __shfl_xor(dot, off);
            msq += __shfl_xor(msq, off);
        }
        if (l16 == 0) {
            const float sim = dot / (kn * sqrtf(msq) + EPS);
            s_out[(size_t)b * L + l0 + p * 4 + sub] = bt * sim;
        }
    }
}

// ---------------------------------------------------------------------------
// Kernel C: per-row finish. grid = B, block = 1024 (16 waves), 4 elems/thread.
// Shuffle-based reductions; conv from LDS; fast pow = exp2(g*log2(x)) (x>0).
// ---------------------------------------------------------------------------
__global__ __launch_bounds__(1024) void finish_kernel(
    const float* __restrict__ s,
    const float* __restrict__ W_old,
    const float* __restrict__ shiftv,
    const float* __restrict__ gate,
    const float* __restrict__ gamma,
    float* __restrict__ out)
{
    const int b    = blockIdx.x;
    const int t    = threadIdx.x;        // 0..1023
    const int wid  = t >> 6;
    const int lane = t & 63;

    __shared__ float w[L];               // 16 KiB
    __shared__ float partial[16];
    __shared__ float sh[S];

    // ---- load + block max
    float vals[4];
    float mx = -1e30f;
#pragma unroll
    for (int i = 0; i < 4; ++i) {
        vals[i] = s[(size_t)b * L + t + i * 1024];
        mx = fmaxf(mx, vals[i]);
    }
#pragma unroll
    for (int off = 32; off > 0; off >>= 1) mx = fmaxf(mx, __shfl_xor(mx, off));
    if (lane == 0) partial[wid] = mx;
    __syncthreads();
    float m = partial[0];
#pragma unroll
    for (int j = 1; j < 16; ++j) m = fmaxf(m, partial[j]);
    __syncthreads();

    // ---- exp + block sum
    float sum = 0.f;
#pragma unroll
    for (int i = 0; i < 4; ++i) {
        vals[i] = __expf(vals[i] - m);
        sum += vals[i];
    }
#pragma unroll
    for (int off = 32; off > 0; off >>= 1) sum += __shfl_xor(sum, off);
    if (lane == 0) partial[wid] = sum;
    __syncthreads();
    float tot = 0.f;
#pragma unroll
    for (int j = 0; j < 16; ++j) tot += partial[j];
    const float invsum = 1.f / tot;
    __syncthreads();

    // ---- gate-interpolate into LDS row
    const float g = gate[b];
#pragma unroll
    for (int i = 0; i < 4; ++i) {
        const int l = t + i * 1024;
        w[l] = fmaf(g, W_old[(size_t)b * L + l], (1.f - g) * (vals[i] * invsum));
    }
    if (t < S) sh[t] = shiftv[b * S + t];
    __syncthreads();

    // ---- circular 7-tap conv + sharpen (w > 0 strictly, so log2 is safe)
    const float gm = gamma[b];
    float pv[4];
    float psum = 0.f;
#pragma unroll
    for (int i = 0; i < 4; ++i) {
        const int l = t + i * 1024;
        float acc = 0.f;
#pragma unroll
        for (int n = 0; n < S; ++n)
            acc = fmaf(sh[n], w[(l - n + 3) & (L - 1)], acc);
        const float p = exp2f(gm * log2f(acc));
        pv[i] = p;
        psum += p;
    }
#pragma unroll
    for (int off = 32; off > 0; off >>= 1) psum += __shfl_xor(psum, off);
    if (lane == 0) partial[wid] = psum;
    __syncthreads();
    float ptot = 0.f;
#pragma unroll
    for (int j = 0; j < 16; ++j) ptot += partial[j];
    const float invp = 1.f / ptot;
#pragma unroll
    for (int i = 0; i < 4; ++i)
        out[(size_t)b * L + t + i * 1024] = pv[i] * invp;
}

// ---------------------------------------------------------------------------
extern "C" void kernel_launch(void* const* d_in, const int* in_sizes, int n_in,
                              void* d_out, int out_size, void* d_ws, size_t ws_size,
                              hipStream_t stream)
{
    const float* Z       = (const float*)d_in[0];
    const float* W_old   = (const float*)d_in[1];
    const float* M       = (const float*)d_in[2];
    const float* key_W   = (const float*)d_in[3];
    const float* key_b   = (const float*)d_in[4];
    const float* shift_W = (const float*)d_in[5];
    const float* shift_b = (const float*)d_in[6];
    const float* beta_W  = (const float*)d_in[7];
    const float* beta_b  = (const float*)d_in[8];
    const float* gate_W  = (const float*)d_in[9];
    const float* gate_b  = (const float*)d_in[10];
    const float* gamma_W = (const float*)d_in[11];
    const float* gamma_b = (const float*)d_in[12];
    float* out = (float*)d_out;

    // workspace layout (floats)
    float* ws     = (float*)d_ws;
    float* k      = ws;                  // B*D
    float* knorm  = k + B * D;
    float* shiftv = knorm + B;
    float* betav  = shiftv + B * S;
    float* gatev  = betav + B;
    float* gammav = gatev + B;
    float* s      = gammav + B;          // B*L

    heads_kernel<<<B, 256, 0, stream>>>(Z, key_W, key_b, shift_W, shift_b,
                                        beta_W, beta_b, gate_W, gate_b,
                                        gamma_W, gamma_b,
                                        k, knorm, shiftv, betav, gatev, gammav);

    sim_kernel<<<B * (L / 64), 256, 0, stream>>>(M, k, knorm, betav, s);

    finish_kernel<<<B, 1024, 0, stream>>>(s, W_old, shiftv, gatev, gammav, out);
}

// Round 5
// 718.613 us; speedup vs baseline: 1.0440x; 1.0278x over previous
//
#include <hip/hip_runtime.h>
#include <math.h>

// Problem dims (fixed by setup_inputs)
constexpr int B  = 128;
constexpr int DZ = 1024;
constexpr int L  = 4096;
constexpr int D  = 256;
constexpr int S  = 7;          // n_shifts_total
constexpr float EPS = 1e-8f;

using f32x4 = __attribute__((ext_vector_type(4))) float;

static __device__ __forceinline__ float softplusf(float x) {
    return fmaxf(x, 0.0f) + log1pf(expf(-fabsf(x)));
}

// ---------------------------------------------------------------------------
// Kernel A: per-batch dense heads. grid = B, block = 256 (== D)
// k[b,:] (tanh GEMV, unroll-16 for 16 loads in flight), plus ONE batched
// 11-row LDS tree reduction for {7 shift logits, beta, gate, gamma, ||k||^2}.
// ---------------------------------------------------------------------------
__global__ __launch_bounds__(256) void heads_kernel(
    const float* __restrict__ Z,
    const float* __restrict__ key_W, const float* __restrict__ key_b,
    const float* __restrict__ shift_W, const float* __restrict__ shift_b,
    const float* __restrict__ beta_W, const float* __restrict__ beta_b,
    const float* __restrict__ gate_W, const float* __restrict__ gate_b,
    const float* __restrict__ gamma_W, const float* __restrict__ gamma_b,
    float* __restrict__ k_out, float* __restrict__ knorm_out,
    float* __restrict__ shift_out, float* __restrict__ beta_out,
    float* __restrict__ gate_out, float* __restrict__ gamma_out)
{
    const int b = blockIdx.x;
    const int t = threadIdx.x;           // one k-column per thread

    constexpr int RSTRIDE = 257;         // pad to break bank aliasing
    __shared__ float zrow[DZ];           // 4 KiB
    __shared__ float red[11 * RSTRIDE];  // ~11.3 KiB

    for (int i = t; i < DZ; i += 256) zrow[i] = Z[b * DZ + i];
    __syncthreads();

    // ---- k = tanh(Z @ key_W + key_b): 16 independent loads in flight
    float acc = 0.f;
    for (int zb = 0; zb < DZ; zb += 16) {
        float p = 0.f;
#pragma unroll
        for (int u = 0; u < 16; ++u)
            p = fmaf(zrow[zb + u], key_W[(zb + u) * D + t], p);
        acc += p;
    }
    const float kv = tanhf(acc + key_b[t]);
    k_out[b * D + t] = kv;

    // ---- 10 small dots + kv^2, all reduced in one batched tree
    float part[11];
#pragma unroll
    for (int j = 0; j < 11; ++j) part[j] = 0.f;
    for (int z = t; z < DZ; z += 256) {
        const float zv = zrow[z];
#pragma unroll
        for (int j = 0; j < S; ++j) part[j] = fmaf(zv, shift_W[z * S + j], part[j]);
        part[7] = fmaf(zv, beta_W[z],  part[7]);
        part[8] = fmaf(zv, gate_W[z],  part[8]);
        part[9] = fmaf(zv, gamma_W[z], part[9]);
    }
    part[10] = kv * kv;

#pragma unroll
    for (int j = 0; j < 11; ++j) red[j * RSTRIDE + t] = part[j];
    __syncthreads();
    for (int st = 128; st > 0; st >>= 1) {
        if (t < st) {
#pragma unroll
            for (int j = 0; j < 11; ++j)
                red[j * RSTRIDE + t] += red[j * RSTRIDE + t + st];
        }
        __syncthreads();
    }

    if (t == 0) {
        float logits[S];
        float mx = -1e30f;
#pragma unroll
        for (int j = 0; j < S; ++j) {
            logits[j] = red[j * RSTRIDE] + shift_b[j];
            mx = fmaxf(mx, logits[j]);
        }
        float sum = 0.f;
#pragma unroll
        for (int j = 0; j < S; ++j) {
            logits[j] = expf(logits[j] - mx);
            sum += logits[j];
        }
        const float inv = 1.f / sum;
#pragma unroll
        for (int j = 0; j < S; ++j) shift_out[b * S + j] = logits[j] * inv;

        beta_out[b]  = softplusf(red[7 * RSTRIDE] + beta_b[0]);
        gate_out[b]  = 1.f / (1.f + expf(-(red[8 * RSTRIDE] + gate_b[0])));
        gamma_out[b] = softplusf(red[9 * RSTRIDE] + gamma_b[0]) + 1.0f;
        knorm_out[b] = sqrtf(red[10 * RSTRIDE]);
    }
}

// ---------------------------------------------------------------------------
// Kernel B: the 512 MiB streamer (memory-bound; target ~6.3 TB/s).
// 16 lanes per row; lane holds 4 float4 = 64 B of its row. ALL 16 row-group
// loads are issued up front (16 outstanding nontemporal loads/thread), then
// 4 reduce phases of 4 rows each. Cross-lane reduce = 4 shfl_xor x 2 vals.
// Block = 4 waves -> 64 rows; grid = B * L/64 = 8192.
// ---------------------------------------------------------------------------
__global__ __launch_bounds__(256) void sim_kernel(
    const float* __restrict__ M,
    const float* __restrict__ k,
    const float* __restrict__ knorm,
    const float* __restrict__ beta,
    float* __restrict__ s_out)
{
    const int blk   = blockIdx.x;
    const int b     = blk >> 6;          // 64 chunks per batch
    const int chunk = blk & 63;
    const int wave  = threadIdx.x >> 6;
    const int lane  = threadIdx.x & 63;
    const int sub   = lane >> 4;         // row within pass group (0..3)
    const int l16   = lane & 15;         // lane within row

    const f32x4* kp = (const f32x4*)(k + b * D);
    f32x4 kv[4];
#pragma unroll
    for (int j = 0; j < 4; ++j) kv[j] = kp[l16 + 16 * j];

    const float kn = knorm[b];
    const float bt = beta[b];

    const int l0 = chunk * 64 + wave * 16;            // wave covers rows l0..l0+15
    const f32x4* Mp = (const f32x4*)(M + ((size_t)b * L + l0) * D);  // row = 64 f32x4

    // issue all 16 loads (4 passes x 4 segs), nontemporal: pure stream, no reuse
    f32x4 mv[4][4];
#pragma unroll
    for (int p = 0; p < 4; ++p)
#pragma unroll
        for (int j = 0; j < 4; ++j)
            mv[p][j] = __builtin_nontemporal_load(
                &Mp[(size_t)(p * 4 + sub) * 64 + l16 + 16 * j]);

#pragma unroll
    for (int p = 0; p < 4; ++p) {
        float dot = 0.f, msq = 0.f;
#pragma unroll
        for (int j = 0; j < 4; ++j) {
#pragma unroll
            for (int c = 0; c < 4; ++c) {
                dot = fmaf(mv[p][j][c], kv[j][c], dot);
                msq = fmaf(mv[p][j][c], mv[p][j][c], msq);
            }
        }
#pragma unroll
        for (int off = 8; off > 0; off >>= 1) {
            dot += __shfl_xor(dot, off);
            msq += __shfl_xor(msq, off);
        }
        if (l16 == 0) {
            const float sim = dot / (kn * sqrtf(msq) + EPS);
            s_out[(size_t)b * L + l0 + p * 4 + sub] = bt * sim;
        }
    }
}

// ---------------------------------------------------------------------------
// Kernel C: per-row finish. grid = B, block = 1024 (16 waves), 4 elems/thread.
// Shuffle-based reductions; conv from LDS; fast pow = exp2(g*log2(x)) (x>0).
// ---------------------------------------------------------------------------
__global__ __launch_bounds__(1024) void finish_kernel(
    const float* __restrict__ s,
    const float* __restrict__ W_old,
    const float* __restrict__ shiftv,
    const float* __restrict__ gate,
    const float* __restrict__ gamma,
    float* __restrict__ out)
{
    const int b    = blockIdx.x;
    const int t    = threadIdx.x;        // 0..1023
    const int wid  = t >> 6;
    const int lane = t & 63;

    __shared__ float w[L];               // 16 KiB
    __shared__ float partial[16];
    __shared__ float sh[S];

    // ---- load + block max
    float vals[4];
    float mx = -1e30f;
#pragma unroll
    for (int i = 0; i < 4; ++i) {
        vals[i] = s[(size_t)b * L + t + i * 1024];
        mx = fmaxf(mx, vals[i]);
    }
#pragma unroll
    for (int off = 32; off > 0; off >>= 1) mx = fmaxf(mx, __shfl_xor(mx, off));
    if (lane == 0) partial[wid] = mx;
    __syncthreads();
    float m = partial[0];
#pragma unroll
    for (int j = 1; j < 16; ++j) m = fmaxf(m, partial[j]);
    __syncthreads();

    // ---- exp + block sum
    float sum = 0.f;
#pragma unroll
    for (int i = 0; i < 4; ++i) {
        vals[i] = __expf(vals[i] - m);
        sum += vals[i];
    }
#pragma unroll
    for (int off = 32; off > 0; off >>= 1) sum += __shfl_xor(sum, off);
    if (lane == 0) partial[wid] = sum;
    __syncthreads();
    float tot = 0.f;
#pragma unroll
    for (int j = 0; j < 16; ++j) tot += partial[j];
    const float invsum = 1.f / tot;
    __syncthreads();

    // ---- gate-interpolate into LDS row
    const float g = gate[b];
#pragma unroll
    for (int i = 0; i < 4; ++i) {
        const int l = t + i * 1024;
        w[l] = fmaf(g, W_old[(size_t)b * L + l], (1.f - g) * (vals[i] * invsum));
    }
    if (t < S) sh[t] = shiftv[b * S + t];
    __syncthreads();

    // ---- circular 7-tap conv + sharpen (w > 0 strictly, so log2 is safe)
    const float gm = gamma[b];
    float pv[4];
    float psum = 0.f;
#pragma unroll
    for (int i = 0; i < 4; ++i) {
        const int l = t + i * 1024;
        float acc = 0.f;
#pragma unroll
        for (int n = 0; n < S; ++n)
            acc = fmaf(sh[n], w[(l - n + 3) & (L - 1)], acc);
        const float p = exp2f(gm * log2f(acc));
        pv[i] = p;
        psum += p;
    }
#pragma unroll
    for (int off = 32; off > 0; off >>= 1) psum += __shfl_xor(psum, off);
    if (lane == 0) partial[wid] = psum;
    __syncthreads();
    float ptot = 0.f;
#pragma unroll
    for (int j = 0; j < 16; ++j) ptot += partial[j];
    const float invp = 1.f / ptot;
#pragma unroll
    for (int i = 0; i < 4; ++i)
        out[(size_t)b * L + t + i * 1024] = pv[i] * invp;
}

// ---------------------------------------------------------------------------
extern "C" void kernel_launch(void* const* d_in, const int* in_sizes, int n_in,
                              void* d_out, int out_size, void* d_ws, size_t ws_size,
                              hipStream_t stream)
{
    const float* Z       = (const float*)d_in[0];
    const float* W_old   = (const float*)d_in[1];
    const float* M       = (const float*)d_in[2];
    const float* key_W   = (const float*)d_in[3];
    const float* key_b   = (const float*)d_in[4];
    const float* shift_W = (const float*)d_in[5];
    const float* shift_b = (const float*)d_in[6];
    const float* beta_W  = (const float*)d_in[7];
    const float* beta_b  = (const float*)d_in[8];
    const float* gate_W  = (const float*)d_in[9];
    const float* gate_b  = (const float*)d_in[10];
    const float* gamma_W = (const float*)d_in[11];
    const float* gamma_b = (const float*)d_in[12];
    float* out = (float*)d_out;

    // workspace layout (floats)
    float* ws     = (float*)d_ws;
    float* k      = ws;                  // B*D
    float* knorm  = k + B * D;
    float* shiftv = knorm + B;
    float* betav  = shiftv + B * S;
    float* gatev  = betav + B;
    float* gammav = gatev + B;
    float* s      = gammav + B;          // B*L

    heads_kernel<<<B, 256, 0, stream>>>(Z, key_W, key_b, shift_W, shift_b,
                                        beta_W, beta_b, gate_W, gate_b,
                                        gamma_W, gamma_b,
                                        k, knorm, shiftv, betav, gatev, gammav);

    sim_kernel<<<B * (L / 64), 256, 0, stream>>>(M, k, knorm, betav, s);

    finish_kernel<<<B, 1024, 0, stream>>>(s, W_old, shiftv, gatev, gammav, out);
}